// Round 2
// baseline (3459.427 us; speedup 1.0000x reference)
//
#include <hip/hip_runtime.h>
#include <math.h>

#define SEQ 4096
#define BATCH 8
#define NIN 1024
#define NH 256
#define NOUT 128
#define M (SEQ*BATCH)   // 32768

// ---------------- K1: xp = x @ W_xh + b_i2h  (M x NIN) @ (NIN x NH) ----------------
// grid: (M/64)*(NH/64) = 512*4 = 2048 blocks, 256 threads
__global__ __launch_bounds__(256) void k_xproj(const float* __restrict__ x,
                                               const float* __restrict__ Wi2h,
                                               const float* __restrict__ bi2h,
                                               float* __restrict__ xp) {
    __shared__ __align__(16) float At[32][64];  // transposed A tile [k][m]
    __shared__ __align__(16) float Bt[32][64];  // B tile [k][n]
    int bid = blockIdx.x;
    int bn_blk = bid & 3, bm_blk = bid >> 2;
    int m0 = bm_blk * 64, n0 = bn_blk * 64;
    int tid = threadIdx.x;
    int tx = tid & 15, ty = tid >> 4;           // compute mapping: rows ty*4.., cols tx*4..
    int lr = tid >> 3;                          // 0..31 (A load row)
    int lc = tid & 7;                           // 0..7  (A load col group, k)
    int bk = tid >> 4;                          // 0..15 (B load row, k)
    int bn = (tid & 15) * 4;                    // 0..60 (B load col)

    float acc[4][4];
    #pragma unroll
    for (int i = 0; i < 4; i++)
        #pragma unroll
        for (int j = 0; j < 4; j++) acc[i][j] = 0.f;

    for (int k0 = 0; k0 < NIN; k0 += 32) {
        float4 a0 = *(const float4*)&x[(size_t)(m0 + lr)      * NIN + k0 + lc * 4];
        float4 a1 = *(const float4*)&x[(size_t)(m0 + lr + 32) * NIN + k0 + lc * 4];
        float4 b0 = *(const float4*)&Wi2h[(size_t)(k0 + bk)      * NH + n0 + bn];
        float4 b1 = *(const float4*)&Wi2h[(size_t)(k0 + bk + 16) * NH + n0 + bn];
        __syncthreads();   // previous iteration's compute done before overwrite
        At[lc*4+0][lr] = a0.x; At[lc*4+1][lr] = a0.y; At[lc*4+2][lr] = a0.z; At[lc*4+3][lr] = a0.w;
        At[lc*4+0][lr+32] = a1.x; At[lc*4+1][lr+32] = a1.y; At[lc*4+2][lr+32] = a1.z; At[lc*4+3][lr+32] = a1.w;
        *(float4*)&Bt[bk][bn]      = b0;
        *(float4*)&Bt[bk+16][bn]   = b1;
        __syncthreads();
        #pragma unroll
        for (int kk = 0; kk < 32; kk++) {
            float4 av = *(const float4*)&At[kk][ty*4];
            float4 bv = *(const float4*)&Bt[kk][tx*4];
            float a[4] = {av.x, av.y, av.z, av.w};
            float b[4] = {bv.x, bv.y, bv.z, bv.w};
            #pragma unroll
            for (int i = 0; i < 4; i++)
                #pragma unroll
                for (int j = 0; j < 4; j++)
                    acc[i][j] = fmaf(a[i], b[j], acc[i][j]);
        }
    }
    float4 bb = *(const float4*)&bi2h[n0 + tx*4];
    float bias[4] = {bb.x, bb.y, bb.z, bb.w};
    #pragma unroll
    for (int i = 0; i < 4; i++) {
        float4 v = make_float4(acc[i][0] + bias[0], acc[i][1] + bias[1],
                               acc[i][2] + bias[2], acc[i][3] + bias[3]);
        *(float4*)&xp[(size_t)(m0 + ty*4 + i) * NH + n0 + tx*4] = v;
    }
}

// ---------------- K2: sequential scan, one block per batch ----------------
// h_new[j] = tanh(xp[t][b][j] + sum_k h[k]*W_hh[k][j]);  hs[t][b][j] = h_new[j]
// 512 threads: kb = tid>>7 (k-block of 64 rows), c0 = (tid&127)*2 (column pair)
__global__ __launch_bounds__(512) void k_scan(const float* __restrict__ Wi2h,
                                              const float* __restrict__ h0,
                                              const float* __restrict__ xp,
                                              float* __restrict__ hs) {
    __shared__ __align__(16) float h_lds[NH];
    __shared__ __align__(16) float psum[4][NH];
    int b = blockIdx.x;
    int tid = threadIdx.x;
    int kb = tid >> 7;            // 0..3
    int c0 = (tid & 127) * 2;     // 0,2,..,254

    // W_hh slice in registers: rows NIN + kb*64 + r, cols c0,c0+1
    float2 w[64];
    #pragma unroll
    for (int r = 0; r < 64; r++)
        w[r] = *(const float2*)&Wi2h[(size_t)(NIN + kb*64 + r) * NH + c0];

    if (tid < NH) h_lds[tid] = h0[b*NH + tid];
    float2 xc = make_float2(0.f, 0.f), xn = make_float2(0.f, 0.f);
    if (tid < 128) xc = *(const float2*)&xp[(size_t)(0*BATCH + b) * NH + tid*2];
    __syncthreads();

    for (int t = 0; t < SEQ; t++) {
        if (t + 1 < SEQ && tid < 128)
            xn = *(const float2*)&xp[(size_t)((t+1)*BATCH + b) * NH + tid*2];
        // partial dot over this thread's 64 k-rows
        float2 pa = make_float2(0.f, 0.f), pb = make_float2(0.f, 0.f);
        #pragma unroll
        for (int r4 = 0; r4 < 16; r4++) {
            float4 h4 = *(const float4*)&h_lds[kb*64 + r4*4];
            pa.x = fmaf(h4.x, w[r4*4+0].x, pa.x); pa.y = fmaf(h4.x, w[r4*4+0].y, pa.y);
            pb.x = fmaf(h4.y, w[r4*4+1].x, pb.x); pb.y = fmaf(h4.y, w[r4*4+1].y, pb.y);
            pa.x = fmaf(h4.z, w[r4*4+2].x, pa.x); pa.y = fmaf(h4.z, w[r4*4+2].y, pa.y);
            pb.x = fmaf(h4.w, w[r4*4+3].x, pb.x); pb.y = fmaf(h4.w, w[r4*4+3].y, pb.y);
        }
        *(float2*)&psum[kb][c0] = make_float2(pa.x + pb.x, pa.y + pb.y);
        __syncthreads();
        if (tid < 128) {
            int j2 = tid * 2;
            float2 s0 = *(const float2*)&psum[0][j2];
            float2 s1 = *(const float2*)&psum[1][j2];
            float2 s2 = *(const float2*)&psum[2][j2];
            float2 s3 = *(const float2*)&psum[3][j2];
            float sx = s0.x + s1.x + s2.x + s3.x + xc.x;
            float sy = s0.y + s1.y + s2.y + s3.y + xc.y;
            float hx = tanhf(sx), hy = tanhf(sy);
            h_lds[j2] = hx; h_lds[j2+1] = hy;
            *(float2*)&hs[(size_t)(t*BATCH + b) * NH + j2] = make_float2(hx, hy);
        }
        xc = xn;
        __syncthreads();
    }
}

// ---------------- K3: out = hs @ W_h2o + b_h2o  (M x NH) @ (NH x NOUT) ----------------
// grid: (M/128 row tiles) * 2 col-halves = 512 blocks, 256 threads
__global__ __launch_bounds__(256) void k_out(const float* __restrict__ hs,
                                             const float* __restrict__ Wh2o,
                                             const float* __restrict__ bh2o,
                                             float* __restrict__ out) {
    __shared__ float Wl[NH][64];   // 64 KB: W_h2o columns half*64..+63
    __shared__ float Hl[8][NH];    // 8 KB
    int bid = blockIdx.x;
    int half = bid & 1;
    int rt = bid >> 1;             // 0..255 -> rows rt*128..+127
    int tid = threadIdx.x;

    for (int i = tid; i < NH*64; i += 256) {
        int k = i >> 6, o = i & 63;
        Wl[k][o] = Wh2o[(size_t)k*NOUT + half*64 + o];
    }
    int o = tid & 63, g = tid >> 6;   // g = 0..3, rows g*2, g*2+1 within tile
    float bias = bh2o[half*64 + o];

    for (int tile = 0; tile < 16; tile++) {
        int r0 = rt*128 + tile*8;
        __syncthreads();   // W staged (tile 0) / previous tile compute done
        for (int i = tid; i < 8*NH; i += 256)
            Hl[i >> 8][i & 255] = hs[(size_t)r0*NH + i];
        __syncthreads();
        float a0 = 0.f, a1 = 0.f;
        int r = g * 2;
        #pragma unroll 8
        for (int k = 0; k < NH; k++) {
            float wv = Wl[k][o];
            a0 = fmaf(Hl[r][k],   wv, a0);
            a1 = fmaf(Hl[r+1][k], wv, a1);
        }
        out[(size_t)(r0 + r)     * NOUT + half*64 + o] = a0 + bias;
        out[(size_t)(r0 + r + 1) * NOUT + half*64 + o] = a1 + bias;
    }
}

extern "C" void kernel_launch(void* const* d_in, const int* in_sizes, int n_in,
                              void* d_out, int out_size, void* d_ws, size_t ws_size,
                              hipStream_t stream) {
    const float* x    = (const float*)d_in[0];
    const float* h0   = (const float*)d_in[1];
    const float* Wi2h = (const float*)d_in[2];
    const float* bi2h = (const float*)d_in[3];
    const float* Wh2o = (const float*)d_in[4];
    const float* bh2o = (const float*)d_in[5];
    float* out = (float*)d_out;

    float* xp = (float*)d_ws;                     // M*NH f32 = 32 MB
    float* hs = xp + (size_t)M * NH;              // M*NH f32 = 32 MB

    k_xproj<<<dim3(2048), dim3(256), 0, stream>>>(x, Wi2h, bi2h, xp);
    k_scan <<<dim3(BATCH), dim3(512), 0, stream>>>(Wi2h, h0, xp, hs);
    k_out  <<<dim3(512), dim3(256), 0, stream>>>(hs, Wh2o, bh2o, out);
}